// Round 1
// baseline (149.587 us; speedup 1.0000x reference)
//
#include <hip/hip_runtime.h>
#include <hip/hip_bf16.h>

#define NUM_MOLECULES 262144
#define NUM_ATOMS     8388608
#define TABLE_SIZE    100
#define CHUNK         32   // atoms per thread = 128 B = one cache line of each int array

// Kernel 1: initialize output with energy_readout (d_out is poisoned 0xAA each call)
__global__ void init_out_kernel(const float* __restrict__ energy,
                                float* __restrict__ out, int n4) {
    int i = blockIdx.x * blockDim.x + threadIdx.x;
    if (i < n4) {
        reinterpret_cast<float4*>(out)[i] =
            reinterpret_cast<const float4*>(energy)[i];
    }
}

// Kernel 2: per-thread chunked segmented sum over sorted molecule indices.
// Each thread handles CHUNK contiguous atoms; emits one atomicAdd per
// segment boundary it sees (avg ~2 per thread).
__global__ void accum_kernel(const int* __restrict__ atomic_numbers,
                             const int* __restrict__ mol_idx,
                             const float* __restrict__ table,
                             float* __restrict__ out) {
    __shared__ float se[TABLE_SIZE];
    for (int t = threadIdx.x; t < TABLE_SIZE; t += blockDim.x)
        se[t] = table[t];
    __syncthreads();

    long long base = (long long)(blockIdx.x * blockDim.x + threadIdx.x) * CHUNK;
    if (base >= NUM_ATOMS) return;

    const int4* z4 = reinterpret_cast<const int4*>(atomic_numbers + base);
    const int4* m4 = reinterpret_cast<const int4*>(mol_idx + base);

    float acc = 0.0f;
    int cur = -1;

#pragma unroll
    for (int j = 0; j < CHUNK / 4; ++j) {
        int4 zz = z4[j];
        int4 mm = m4[j];
        int za[4] = {zz.x, zz.y, zz.z, zz.w};
        int ma[4] = {mm.x, mm.y, mm.z, mm.w};
#pragma unroll
        for (int k = 0; k < 4; ++k) {
            float v = se[za[k]];
            if (ma[k] == cur) {
                acc += v;
            } else {
                if (cur >= 0) atomicAdd(out + cur, acc);
                cur = ma[k];
                acc = v;
            }
        }
    }
    if (cur >= 0) atomicAdd(out + cur, acc);
}

extern "C" void kernel_launch(void* const* d_in, const int* in_sizes, int n_in,
                              void* d_out, int out_size, void* d_ws, size_t ws_size,
                              hipStream_t stream) {
    const float* energy_readout = (const float*)d_in[0];
    const int*   atomic_numbers = (const int*)d_in[1];
    const int*   mol_idx        = (const int*)d_in[2];
    const float* table          = (const float*)d_in[3];
    float* out = (float*)d_out;

    // Kernel 1: copy energy_readout -> out (float4)
    int n4 = NUM_MOLECULES / 4;                 // 65536
    int b1 = 256;
    int g1 = (n4 + b1 - 1) / b1;                // 256 blocks
    init_out_kernel<<<g1, b1, 0, stream>>>(energy_readout, out, n4);

    // Kernel 2: segmented accumulation
    int n_threads = NUM_ATOMS / CHUNK;          // 262144
    int b2 = 256;
    int g2 = n_threads / b2;                    // 1024 blocks
    accum_kernel<<<g2, b2, 0, stream>>>(atomic_numbers, mol_idx, table, out);
}

// Round 2
// 114.907 us; speedup vs baseline: 1.3018x; 1.3018x over previous
//
#include <hip/hip_runtime.h>
#include <hip/hip_bf16.h>

#define NUM_MOLECULES 262144
#define NUM_ATOMS     8388608
#define TABLE_SIZE    100
#define BLOCK         256
#define CPT           16                  // atoms per thread
#define TILE          (BLOCK * CPT)       // 4096 atoms per block
#define PAD(i)        ((i) + ((i) >> 4))  // +1 word per 16 -> chunk stride 17 (coprime w/ 32 banks)

// Kernel 1: out[m] = energy_readout[m]  (d_out is poisoned 0xAA before every call)
__global__ void init_out_kernel(const float* __restrict__ energy,
                                float* __restrict__ out, int n4) {
    int i = blockIdx.x * blockDim.x + threadIdx.x;
    if (i < n4) {
        reinterpret_cast<float4*>(out)[i] =
            reinterpret_cast<const float4*>(energy)[i];
    }
}

// Kernel 2: coalesced tile staging -> padded LDS transpose -> per-thread
// run-length segmented sum over 16 contiguous atoms -> atomicAdd per run.
__global__ void __launch_bounds__(BLOCK, 4)
accum_kernel(const int* __restrict__ atomic_numbers,
             const int* __restrict__ mol_idx,
             const float* __restrict__ table,
             float* __restrict__ out) {
    __shared__ float tab[TABLE_SIZE];
    __shared__ float sval[PAD(TILE)];
    __shared__ int   smol[PAD(TILE)];

    for (int t = threadIdx.x; t < TABLE_SIZE; t += BLOCK)
        tab[t] = table[t];
    __syncthreads();

    const int tile_base = blockIdx.x * TILE;
    const int4* z4 = reinterpret_cast<const int4*>(atomic_numbers + tile_base);
    const int4* m4 = reinterpret_cast<const int4*>(mol_idx + tile_base);

    // Coalesced staging: lane-striped int4 loads, each 128B line touched by
    // exactly one wave instruction, fully consumed. Gather se[z] on the fly.
#pragma unroll
    for (int k = 0; k < TILE / 4 / BLOCK; ++k) {
        int idx = k * BLOCK + threadIdx.x;       // int4 index within tile
        int4 zz = z4[idx];
        int4 mm = m4[idx];
        float4 vv = make_float4(tab[zz.x], tab[zz.y], tab[zz.z], tab[zz.w]);
        int a = idx * 4;                          // atom index within tile
        int p = PAD(a);                           // 4 consecutive atoms never cross a pad
        *reinterpret_cast<float4*>(&sval[p]) = vv;
        *reinterpret_cast<int4*>(&smol[p])   = mm;
    }
    __syncthreads();

    // Per-thread segmented sum over its 16 contiguous atoms (LDS stride 17).
    int p = PAD(threadIdx.x * CPT);               // = 17 * threadIdx.x
    int   cur = smol[p];
    float acc = sval[p];
#pragma unroll
    for (int j = 1; j < CPT; ++j) {
        int   m = smol[p + j];
        float v = sval[p + j];
        if (m == cur) {
            acc += v;
        } else {
            atomicAdd(out + cur, acc);
            cur = m;
            acc = v;
        }
    }
    atomicAdd(out + cur, acc);
}

extern "C" void kernel_launch(void* const* d_in, const int* in_sizes, int n_in,
                              void* d_out, int out_size, void* d_ws, size_t ws_size,
                              hipStream_t stream) {
    const float* energy_readout = (const float*)d_in[0];
    const int*   atomic_numbers = (const int*)d_in[1];
    const int*   mol_idx        = (const int*)d_in[2];
    const float* table          = (const float*)d_in[3];
    float* out = (float*)d_out;

    // Kernel 1: copy energy_readout -> out (float4)
    int n4 = NUM_MOLECULES / 4;                 // 65536
    int b1 = 256;
    int g1 = (n4 + b1 - 1) / b1;                // 64 blocks of 1024? no: 256 blocks of 256
    init_out_kernel<<<g1, b1, 0, stream>>>(energy_readout, out, n4);

    // Kernel 2: segmented accumulation, 2048 blocks x 256 threads
    int g2 = NUM_ATOMS / TILE;                  // 2048
    accum_kernel<<<g2, BLOCK, 0, stream>>>(atomic_numbers, mol_idx, table, out);
}

// Round 3
// 100.174 us; speedup vs baseline: 1.4933x; 1.1471x over previous
//
#include <hip/hip_runtime.h>
#include <hip/hip_bf16.h>

#define NUM_MOLECULES 262144
#define NUM_ATOMS     8388608
#define TABLE_SIZE    100
#define BLOCK         256
#define CPT           4                   // atoms per thread, one int4 of z + one of m

// Kernel 1: out[m] = energy_readout[m]  (d_out is poisoned 0xAA before every call)
__global__ void init_out_kernel(const float* __restrict__ energy,
                                float* __restrict__ out, int n4) {
    int i = blockIdx.x * blockDim.x + threadIdx.x;
    if (i < n4) {
        reinterpret_cast<float4*>(out)[i] =
            reinterpret_cast<const float4*>(energy)[i];
    }
}

// Kernel 2: per-thread parse of 4 sorted atoms + wave-level head-flagged
// segmented scan (Hillis-Steele over 64 lanes) -> ~1 atomicAdd per segment run.
// No data LDS, no __syncthreads in the hot path, fully coalesced int4 loads.
__global__ void __launch_bounds__(BLOCK)
accum_kernel(const int* __restrict__ atomic_numbers,
             const int* __restrict__ mol_idx,
             const float* __restrict__ table,
             float* __restrict__ out) {
    __shared__ float tab[TABLE_SIZE];
    if (threadIdx.x < TABLE_SIZE) tab[threadIdx.x] = table[threadIdx.x];
    __syncthreads();

    const int tid = blockIdx.x * blockDim.x + threadIdx.x;
    const int4 zz = reinterpret_cast<const int4*>(atomic_numbers)[tid];
    const int4 mm = reinterpret_cast<const int4*>(mol_idx)[tid];

    const float v0 = tab[zz.x], v1 = tab[zz.y], v2 = tab[zz.z], v3 = tab[zz.w];

    // ---- local parse of 4 atoms into head run / interior runs / tail run ----
    int   curm = mm.x;
    float run  = v0;
    float head_sum = 0.0f;     // sum of leading run (valid iff nbound > 0)
    int   nbound = 0;          // number of molecule changes inside this thread
    const int   m_arr[3] = {mm.y, mm.z, mm.w};
    const float v_arr[3] = {v1, v2, v3};
#pragma unroll
    for (int j = 0; j < 3; ++j) {
        if (m_arr[j] == curm) {
            run += v_arr[j];
        } else {
            if (nbound == 0) head_sum = run;            // head run closes (may connect backward)
            else atomicAdd(out + curm, run);            // interior complete run
            ++nbound;
            curm = m_arr[j];
            run  = v_arr[j];
        }
    }
    const int   head_mol = mm.x;
    const int   tail_mol = curm;       // == mm.w
    const float tail_sum = run;

    const int lane = threadIdx.x & 63;

    // ---- cross-lane connectivity ----
    const int prev_tail = __shfl_up(tail_mol, 1);
    const bool connect = (lane > 0) && (head_mol == prev_tail);
    // "open": incoming run flows through this whole lane into its tail
    const bool open = (nbound == 0) && connect;

    // ---- segmented inclusive scan of tail_sum, head flag = !open ----
    float c = tail_sum;
    int   f = open ? 0 : 1;
#pragma unroll
    for (int d = 1; d < 64; d <<= 1) {
        float cp = __shfl_up(c, d);
        int   fp = __shfl_up(f, d);
        if (lane >= d && !f) {
            c += cp;
            f |= fp;
        }
    }
    // c = sum of the open tail-run chain ending at this lane

    // ---- flush the incoming head run (boundary lanes close it) ----
    const float cin = __shfl_up(c, 1);   // chain total through lane-1 (valid iff connect)
    if (nbound > 0) {
        atomicAdd(out + head_mol, head_sum + (connect ? cin : 0.0f));
    }

    // ---- flush tail chains not absorbed by the next lane ----
    const int next_connect = __shfl_down((int)connect, 1);
    const bool chain_end = (lane == 63) || !next_connect;
    if (chain_end) {
        atomicAdd(out + tail_mol, c);
    }
}

extern "C" void kernel_launch(void* const* d_in, const int* in_sizes, int n_in,
                              void* d_out, int out_size, void* d_ws, size_t ws_size,
                              hipStream_t stream) {
    const float* energy_readout = (const float*)d_in[0];
    const int*   atomic_numbers = (const int*)d_in[1];
    const int*   mol_idx        = (const int*)d_in[2];
    const float* table          = (const float*)d_in[3];
    float* out = (float*)d_out;

    // Kernel 1: copy energy_readout -> out (float4)
    int n4 = NUM_MOLECULES / 4;                 // 65536
    int b1 = 256;
    int g1 = (n4 + b1 - 1) / b1;                // 256 blocks
    init_out_kernel<<<g1, b1, 0, stream>>>(energy_readout, out, n4);

    // Kernel 2: segmented accumulation, 8192 blocks x 256 threads, 4 atoms/thread
    int g2 = NUM_ATOMS / (BLOCK * CPT);         // 8192
    accum_kernel<<<g2, BLOCK, 0, stream>>>(atomic_numbers, mol_idx, table, out);
}

// Round 4
// 100.004 us; speedup vs baseline: 1.4958x; 1.0017x over previous
//
#include <hip/hip_runtime.h>
#include <hip/hip_bf16.h>

#define NUM_MOLECULES 262144
#define NUM_ATOMS     8388608
#define TABLE_SIZE    100
#define BLOCK         256
#define CPT           8                   // atoms per thread: two int4 of z + two of m

// Kernel 1: out[m] = energy_readout[m]  (d_out is poisoned 0xAA before every call)
__global__ void init_out_kernel(const float* __restrict__ energy,
                                float* __restrict__ out, int n4) {
    int i = blockIdx.x * blockDim.x + threadIdx.x;
    if (i < n4) {
        reinterpret_cast<float4*>(out)[i] =
            reinterpret_cast<const float4*>(energy)[i];
    }
}

// Kernel 2: per-thread parse of 8 sorted atoms + wave-level head-flagged
// segmented scan (Hillis-Steele over 64 lanes) -> ~1 atomicAdd per segment run.
// No data LDS, no __syncthreads in the hot path, fully coalesced int4 loads.
__global__ void __launch_bounds__(BLOCK)
accum_kernel(const int* __restrict__ atomic_numbers,
             const int* __restrict__ mol_idx,
             const float* __restrict__ table,
             float* __restrict__ out) {
    __shared__ float tab[TABLE_SIZE];
    if (threadIdx.x < TABLE_SIZE) tab[threadIdx.x] = table[threadIdx.x];
    __syncthreads();

    const int tid = blockIdx.x * blockDim.x + threadIdx.x;
    const int4* zp = reinterpret_cast<const int4*>(atomic_numbers);
    const int4* mp = reinterpret_cast<const int4*>(mol_idx);
    const int4 zzA = zp[2 * tid], zzB = zp[2 * tid + 1];
    const int4 mmA = mp[2 * tid], mmB = mp[2 * tid + 1];

    const int m_all[8] = {mmA.x, mmA.y, mmA.z, mmA.w, mmB.x, mmB.y, mmB.z, mmB.w};
    const float v_all[8] = {tab[zzA.x], tab[zzA.y], tab[zzA.z], tab[zzA.w],
                            tab[zzB.x], tab[zzB.y], tab[zzB.z], tab[zzB.w]};

    // ---- local parse of 8 atoms into head run / interior runs / tail run ----
    int   curm = m_all[0];
    float run  = v_all[0];
    float head_sum = 0.0f;     // sum of leading run (valid iff nbound > 0)
    int   nbound = 0;          // number of molecule changes inside this thread
#pragma unroll
    for (int j = 1; j < CPT; ++j) {
        if (m_all[j] == curm) {
            run += v_all[j];
        } else {
            if (nbound == 0) head_sum = run;            // head run closes (may connect backward)
            else atomicAdd(out + curm, run);            // interior complete run
            ++nbound;
            curm = m_all[j];
            run  = v_all[j];
        }
    }
    const int   head_mol = m_all[0];
    const int   tail_mol = curm;       // == m_all[7]
    const float tail_sum = run;

    const int lane = threadIdx.x & 63;

    // ---- cross-lane connectivity ----
    const int prev_tail = __shfl_up(tail_mol, 1);
    const bool connect = (lane > 0) && (head_mol == prev_tail);
    // "open": incoming run flows through this whole lane into its tail
    const bool open = (nbound == 0) && connect;

    // ---- segmented inclusive scan of tail_sum, head flag = !open ----
    float c = tail_sum;
    int   f = open ? 0 : 1;
#pragma unroll
    for (int d = 1; d < 64; d <<= 1) {
        float cp = __shfl_up(c, d);
        int   fp = __shfl_up(f, d);
        if (lane >= d && !f) {
            c += cp;
            f |= fp;
        }
    }
    // c = sum of the open tail-run chain ending at this lane

    // ---- flush the incoming head run (boundary lanes close it) ----
    const float cin = __shfl_up(c, 1);   // chain total through lane-1 (valid iff connect)
    if (nbound > 0) {
        atomicAdd(out + head_mol, head_sum + (connect ? cin : 0.0f));
    }

    // ---- flush tail chains not absorbed by the next lane ----
    const int next_connect = __shfl_down((int)connect, 1);
    const bool chain_end = (lane == 63) || !next_connect;
    if (chain_end) {
        atomicAdd(out + tail_mol, c);
    }
}

extern "C" void kernel_launch(void* const* d_in, const int* in_sizes, int n_in,
                              void* d_out, int out_size, void* d_ws, size_t ws_size,
                              hipStream_t stream) {
    const float* energy_readout = (const float*)d_in[0];
    const int*   atomic_numbers = (const int*)d_in[1];
    const int*   mol_idx        = (const int*)d_in[2];
    const float* table          = (const float*)d_in[3];
    float* out = (float*)d_out;

    // Kernel 1: copy energy_readout -> out (float4)
    int n4 = NUM_MOLECULES / 4;                 // 65536
    int b1 = 256;
    int g1 = (n4 + b1 - 1) / b1;                // 256 blocks
    init_out_kernel<<<g1, b1, 0, stream>>>(energy_readout, out, n4);

    // Kernel 2: segmented accumulation, 4096 blocks x 256 threads, 8 atoms/thread
    int g2 = NUM_ATOMS / (BLOCK * CPT);         // 4096
    accum_kernel<<<g2, BLOCK, 0, stream>>>(atomic_numbers, mol_idx, table, out);
}